// Round 1
// baseline (606.941 us; speedup 1.0000x reference)
//
#include <hip/hip_runtime.h>

#define NG 128  // NUM_GRAPHS

__device__ __forceinline__ int seg_cross(float2 p1, float2 p2, float2 p3, float2 p4) {
    const float eps = 1e-5f;
    float ax = p4.x - p3.x, ay = p4.y - p3.y;
    float d1 = ax * (p1.y - p3.y) - ay * (p1.x - p3.x);
    float d2 = ax * (p2.y - p3.y) - ay * (p2.x - p3.x);
    float bx = p2.x - p1.x, by = p2.y - p1.y;
    float d3 = bx * (p3.y - p1.y) - by * (p3.x - p1.x);
    float d4 = bx * (p4.y - p1.y) - by * (p4.x - p1.x);
    return (d1 * d2 < -eps) & (d3 * d4 < -eps);
}

// Kernel 1: per-block 128-bin LDS histogram -> partials[bin * nblocks + blockIdx]
__global__ __launch_bounds__(256) void xing_partials(
    const float2* __restrict__ pos, const int* __restrict__ batch,
    const int* __restrict__ epi, float* __restrict__ partials,
    int P, int nquads, int nblocks)
{
    __shared__ int bins[NG];
    for (int i = threadIdx.x; i < NG; i += 256) bins[i] = 0;
    __syncthreads();

    const int4* s1p = (const int4*)(epi);
    const int4* s2p = (const int4*)(epi + (size_t)P);
    const int4* e1p = (const int4*)(epi + 2 * (size_t)P);
    const int4* e2p = (const int4*)(epi + 3 * (size_t)P);

    int tid = blockIdx.x * 256 + threadIdx.x;
    int stride = gridDim.x * 256;

    for (int q = tid; q < nquads; q += stride) {
        int4 s1 = s1p[q];
        int4 e1 = e1p[q];
        int4 s2 = s2p[q];
        int4 e2 = e2p[q];

        // issue all gathers, then test
        float2 a1 = pos[s1.x], a2 = pos[e1.x], a3 = pos[s2.x], a4 = pos[e2.x];
        float2 b1 = pos[s1.y], b2 = pos[e1.y], b3 = pos[s2.y], b4 = pos[e2.y];
        float2 c1 = pos[s1.z], c2 = pos[e1.z], c3 = pos[s2.z], c4 = pos[e2.z];
        float2 d1 = pos[s1.w], d2 = pos[e1.w], d3 = pos[s2.w], d4 = pos[e2.w];
        int ba = batch[s1.x], bb = batch[s1.y], bc = batch[s1.z], bd = batch[s1.w];

        if (seg_cross(a1, a2, a3, a4)) atomicAdd(&bins[ba], 1);
        if (seg_cross(b1, b2, b3, b4)) atomicAdd(&bins[bb], 1);
        if (seg_cross(c1, c2, c3, c4)) atomicAdd(&bins[bc], 1);
        if (seg_cross(d1, d2, d3, d4)) atomicAdd(&bins[bd], 1);
    }

    // tail (P not multiple of 4)
    for (int i = nquads * 4 + tid; i < P; i += stride) {
        int s1 = epi[i];
        int s2 = epi[(size_t)P + i];
        int e1 = epi[2 * (size_t)P + i];
        int e2 = epi[3 * (size_t)P + i];
        if (seg_cross(pos[s1], pos[e1], pos[s2], pos[e2]))
            atomicAdd(&bins[batch[s1]], 1);
    }

    __syncthreads();
    for (int i = threadIdx.x; i < NG; i += 256)
        partials[(size_t)i * nblocks + blockIdx.x] = (float)bins[i];
}

// Kernel 2: one block per bin, coalesced row sum
__global__ __launch_bounds__(256) void reduce_partials(
    const float* __restrict__ partials, float* __restrict__ out, int nblocks)
{
    int bin = blockIdx.x;
    const float* row = partials + (size_t)bin * nblocks;
    float sum = 0.0f;
    for (int i = threadIdx.x; i < nblocks; i += 256) sum += row[i];
    #pragma unroll
    for (int off = 32; off > 0; off >>= 1) sum += __shfl_down(sum, off, 64);
    __shared__ float ws[4];
    int lane = threadIdx.x & 63, wid = threadIdx.x >> 6;
    if (lane == 0) ws[wid] = sum;
    __syncthreads();
    if (threadIdx.x == 0) out[bin] = ws[0] + ws[1] + ws[2] + ws[3];
}

// ---- atomic fallback path (only if ws_size is tiny) ----
__global__ void zero_out_k(float* out) { out[threadIdx.x] = 0.0f; }

__global__ __launch_bounds__(256) void xing_atomic(
    const float2* __restrict__ pos, const int* __restrict__ batch,
    const int* __restrict__ epi, float* __restrict__ out, int P, int nquads)
{
    __shared__ int bins[NG];
    for (int i = threadIdx.x; i < NG; i += 256) bins[i] = 0;
    __syncthreads();
    const int4* s1p = (const int4*)(epi);
    const int4* s2p = (const int4*)(epi + (size_t)P);
    const int4* e1p = (const int4*)(epi + 2 * (size_t)P);
    const int4* e2p = (const int4*)(epi + 3 * (size_t)P);
    int tid = blockIdx.x * 256 + threadIdx.x;
    int stride = gridDim.x * 256;
    for (int q = tid; q < nquads; q += stride) {
        int4 s1 = s1p[q], e1 = e1p[q], s2 = s2p[q], e2 = e2p[q];
        if (seg_cross(pos[s1.x], pos[e1.x], pos[s2.x], pos[e2.x])) atomicAdd(&bins[batch[s1.x]], 1);
        if (seg_cross(pos[s1.y], pos[e1.y], pos[s2.y], pos[e2.y])) atomicAdd(&bins[batch[s1.y]], 1);
        if (seg_cross(pos[s1.z], pos[e1.z], pos[s2.z], pos[e2.z])) atomicAdd(&bins[batch[s1.z]], 1);
        if (seg_cross(pos[s1.w], pos[e1.w], pos[s2.w], pos[e2.w])) atomicAdd(&bins[batch[s1.w]], 1);
    }
    for (int i = nquads * 4 + tid; i < P; i += stride) {
        int s1 = epi[i], s2 = epi[(size_t)P + i], e1 = epi[2 * (size_t)P + i], e2 = epi[3 * (size_t)P + i];
        if (seg_cross(pos[s1], pos[e1], pos[s2], pos[e2])) atomicAdd(&bins[batch[s1]], 1);
    }
    __syncthreads();
    for (int i = threadIdx.x; i < NG; i += 256) {
        int v = bins[i];
        if (v) atomicAdd(&out[i], (float)v);
    }
}

extern "C" void kernel_launch(void* const* d_in, const int* in_sizes, int n_in,
                              void* d_out, int out_size, void* d_ws, size_t ws_size,
                              hipStream_t stream) {
    const float2* pos  = (const float2*)d_in[0];   // node_pos [N,2] f32
    const int* batch   = (const int*)d_in[3];      // batch_index [N]
    const int* epi     = (const int*)d_in[4];      // edge_pair_index [2,2,P]
    float* out         = (float*)d_out;            // [128] f32

    int P = in_sizes[4] / 4;
    int nquads = P / 4;

    int nblocks = 2048;
    size_t need = (size_t)NG * (size_t)nblocks * sizeof(float);
    if (ws_size < need) {
        nblocks = (int)(ws_size / ((size_t)NG * sizeof(float)));
        if (nblocks > 2048) nblocks = 2048;
    }

    if (nblocks >= 64) {
        float* partials = (float*)d_ws;
        xing_partials<<<nblocks, 256, 0, stream>>>(pos, batch, epi, partials, P, nquads, nblocks);
        reduce_partials<<<NG, 256, 0, stream>>>(partials, out, nblocks);
    } else {
        zero_out_k<<<1, NG, 0, stream>>>(out);
        xing_atomic<<<1024, 256, 0, stream>>>(pos, batch, epi, out, P, nquads);
    }
}

// Round 3
// 575.466 us; speedup vs baseline: 1.0547x; 1.0547x over previous
//
#include <hip/hip_runtime.h>

#define NG 128  // NUM_GRAPHS

typedef int v4i __attribute__((ext_vector_type(4)));  // native vector: nontemporal-load OK

__device__ __forceinline__ int seg_cross(float2 p1, float2 p2, float2 p3, float2 p4) {
    const float eps = 1e-5f;
    float ax = p4.x - p3.x, ay = p4.y - p3.y;
    float d1 = ax * (p1.y - p3.y) - ay * (p1.x - p3.x);
    float d2 = ax * (p2.y - p3.y) - ay * (p2.x - p3.x);
    float bx = p2.x - p1.x, by = p2.y - p1.y;
    float d3 = bx * (p3.y - p1.y) - by * (p3.x - p1.x);
    float d4 = bx * (p4.y - p1.y) - by * (p4.x - p1.x);
    return (d1 * d2 < -eps) & (d3 * d4 < -eps);
}

// Stage {pos.x, pos.y, batch} into one 16B record so the s1 gather fetches both.
__global__ __launch_bounds__(256) void build_nodes(
    const float2* __restrict__ pos, const int* __restrict__ batch,
    float4* __restrict__ node4, int N)
{
    int i = blockIdx.x * 256 + threadIdx.x;
    if (i < N) {
        float2 p = pos[i];
        node4[i] = make_float4(p.x, p.y, __int_as_float(batch[i]), 0.0f);
    }
}

// Main kernel: 8 pairs/thread, all gathers in flight before use.
__global__ __launch_bounds__(256, 4) void xing_partials8(
    const float4* __restrict__ node4, const float2* __restrict__ pos,
    const int* __restrict__ batch,
    const int* __restrict__ epi, float* __restrict__ partials,
    int P, int nocts, int nblocks)
{
    __shared__ int bins[NG];
    for (int i = threadIdx.x; i < NG; i += 256) bins[i] = 0;
    __syncthreads();

    const v4i* s1p = (const v4i*)(epi);
    const v4i* s2p = (const v4i*)(epi + (size_t)P);
    const v4i* e1p = (const v4i*)(epi + 2 * (size_t)P);
    const v4i* e2p = (const v4i*)(epi + 3 * (size_t)P);

    int tid = blockIdx.x * 256 + threadIdx.x;
    int stride = gridDim.x * 256;

    for (int o = tid; o < nocts; o += stride) {
        // streamed index loads — nontemporal so they don't evict node tables in L2
        v4i s1a = __builtin_nontemporal_load(&s1p[2 * o]);
        v4i s1b = __builtin_nontemporal_load(&s1p[2 * o + 1]);
        v4i e1a = __builtin_nontemporal_load(&e1p[2 * o]);
        v4i e1b = __builtin_nontemporal_load(&e1p[2 * o + 1]);
        v4i s2a = __builtin_nontemporal_load(&s2p[2 * o]);
        v4i s2b = __builtin_nontemporal_load(&s2p[2 * o + 1]);
        v4i e2a = __builtin_nontemporal_load(&e2p[2 * o]);
        v4i e2b = __builtin_nontemporal_load(&e2p[2 * o + 1]);

        int is1[8] = {s1a.x, s1a.y, s1a.z, s1a.w, s1b.x, s1b.y, s1b.z, s1b.w};
        int ie1[8] = {e1a.x, e1a.y, e1a.z, e1a.w, e1b.x, e1b.y, e1b.z, e1b.w};
        int is2[8] = {s2a.x, s2a.y, s2a.z, s2a.w, s2b.x, s2b.y, s2b.z, s2b.w};
        int ie2[8] = {e2a.x, e2a.y, e2a.z, e2a.w, e2b.x, e2b.y, e2b.z, e2b.w};

        float4 n1[8];
        float2 q2[8], q3[8], q4[8];
        #pragma unroll
        for (int j = 0; j < 8; j++) n1[j] = node4[is1[j]];
        #pragma unroll
        for (int j = 0; j < 8; j++) q2[j] = pos[ie1[j]];
        #pragma unroll
        for (int j = 0; j < 8; j++) q3[j] = pos[is2[j]];
        #pragma unroll
        for (int j = 0; j < 8; j++) q4[j] = pos[ie2[j]];

        #pragma unroll
        for (int j = 0; j < 8; j++) {
            if (seg_cross(make_float2(n1[j].x, n1[j].y), q2[j], q3[j], q4[j]))
                atomicAdd(&bins[__float_as_int(n1[j].z)], 1);
        }
    }

    // tail (P not multiple of 8) — scalar, uses raw tables
    for (int i = nocts * 8 + tid; i < P; i += stride) {
        int s1 = epi[i];
        int s2 = epi[(size_t)P + i];
        int e1 = epi[2 * (size_t)P + i];
        int e2 = epi[3 * (size_t)P + i];
        if (seg_cross(pos[s1], pos[e1], pos[s2], pos[e2]))
            atomicAdd(&bins[batch[s1]], 1);
    }

    __syncthreads();
    for (int i = threadIdx.x; i < NG; i += 256)
        partials[(size_t)i * nblocks + blockIdx.x] = (float)bins[i];
}

// Round-1 kernel kept as fallback when ws can't hold the node4 table.
__global__ __launch_bounds__(256) void xing_partials_basic(
    const float2* __restrict__ pos, const int* __restrict__ batch,
    const int* __restrict__ epi, float* __restrict__ partials,
    int P, int nquads, int nblocks)
{
    __shared__ int bins[NG];
    for (int i = threadIdx.x; i < NG; i += 256) bins[i] = 0;
    __syncthreads();
    const int4* s1p = (const int4*)(epi);
    const int4* s2p = (const int4*)(epi + (size_t)P);
    const int4* e1p = (const int4*)(epi + 2 * (size_t)P);
    const int4* e2p = (const int4*)(epi + 3 * (size_t)P);
    int tid = blockIdx.x * 256 + threadIdx.x;
    int stride = gridDim.x * 256;
    for (int q = tid; q < nquads; q += stride) {
        int4 s1 = s1p[q], e1 = e1p[q], s2 = s2p[q], e2 = e2p[q];
        float2 a1 = pos[s1.x], a2 = pos[e1.x], a3 = pos[s2.x], a4 = pos[e2.x];
        float2 b1 = pos[s1.y], b2 = pos[e1.y], b3 = pos[s2.y], b4 = pos[e2.y];
        float2 c1 = pos[s1.z], c2 = pos[e1.z], c3 = pos[s2.z], c4 = pos[e2.z];
        float2 d1 = pos[s1.w], d2 = pos[e1.w], d3 = pos[s2.w], d4 = pos[e2.w];
        int ba = batch[s1.x], bb = batch[s1.y], bc = batch[s1.z], bd = batch[s1.w];
        if (seg_cross(a1, a2, a3, a4)) atomicAdd(&bins[ba], 1);
        if (seg_cross(b1, b2, b3, b4)) atomicAdd(&bins[bb], 1);
        if (seg_cross(c1, c2, c3, c4)) atomicAdd(&bins[bc], 1);
        if (seg_cross(d1, d2, d3, d4)) atomicAdd(&bins[bd], 1);
    }
    for (int i = nquads * 4 + tid; i < P; i += stride) {
        int s1 = epi[i], s2 = epi[(size_t)P + i], e1 = epi[2 * (size_t)P + i], e2 = epi[3 * (size_t)P + i];
        if (seg_cross(pos[s1], pos[e1], pos[s2], pos[e2])) atomicAdd(&bins[batch[s1]], 1);
    }
    __syncthreads();
    for (int i = threadIdx.x; i < NG; i += 256)
        partials[(size_t)i * nblocks + blockIdx.x] = (float)bins[i];
}

__global__ __launch_bounds__(256) void reduce_partials(
    const float* __restrict__ partials, float* __restrict__ out, int nblocks)
{
    int bin = blockIdx.x;
    const float* row = partials + (size_t)bin * nblocks;
    float sum = 0.0f;
    for (int i = threadIdx.x; i < nblocks; i += 256) sum += row[i];
    #pragma unroll
    for (int off = 32; off > 0; off >>= 1) sum += __shfl_down(sum, off, 64);
    __shared__ float ws[4];
    int lane = threadIdx.x & 63, wid = threadIdx.x >> 6;
    if (lane == 0) ws[wid] = sum;
    __syncthreads();
    if (threadIdx.x == 0) out[bin] = ws[0] + ws[1] + ws[2] + ws[3];
}

__global__ void zero_out_k(float* out) { out[threadIdx.x] = 0.0f; }

__global__ __launch_bounds__(256) void xing_atomic(
    const float2* __restrict__ pos, const int* __restrict__ batch,
    const int* __restrict__ epi, float* __restrict__ out, int P, int nquads)
{
    __shared__ int bins[NG];
    for (int i = threadIdx.x; i < NG; i += 256) bins[i] = 0;
    __syncthreads();
    const int4* s1p = (const int4*)(epi);
    const int4* s2p = (const int4*)(epi + (size_t)P);
    const int4* e1p = (const int4*)(epi + 2 * (size_t)P);
    const int4* e2p = (const int4*)(epi + 3 * (size_t)P);
    int tid = blockIdx.x * 256 + threadIdx.x;
    int stride = gridDim.x * 256;
    for (int q = tid; q < nquads; q += stride) {
        int4 s1 = s1p[q], e1 = e1p[q], s2 = s2p[q], e2 = e2p[q];
        if (seg_cross(pos[s1.x], pos[e1.x], pos[s2.x], pos[e2.x])) atomicAdd(&bins[batch[s1.x]], 1);
        if (seg_cross(pos[s1.y], pos[e1.y], pos[s2.y], pos[e2.y])) atomicAdd(&bins[batch[s1.y]], 1);
        if (seg_cross(pos[s1.z], pos[e1.z], pos[s2.z], pos[e2.z])) atomicAdd(&bins[batch[s1.z]], 1);
        if (seg_cross(pos[s1.w], pos[e1.w], pos[s2.w], pos[e2.w])) atomicAdd(&bins[batch[s1.w]], 1);
    }
    for (int i = nquads * 4 + tid; i < P; i += stride) {
        int s1 = epi[i], s2 = epi[(size_t)P + i], e1 = epi[2 * (size_t)P + i], e2 = epi[3 * (size_t)P + i];
        if (seg_cross(pos[s1], pos[e1], pos[s2], pos[e2])) atomicAdd(&bins[batch[s1]], 1);
    }
    __syncthreads();
    for (int i = threadIdx.x; i < NG; i += 256) {
        int v = bins[i];
        if (v) atomicAdd(&out[i], (float)v);
    }
}

extern "C" void kernel_launch(void* const* d_in, const int* in_sizes, int n_in,
                              void* d_out, int out_size, void* d_ws, size_t ws_size,
                              hipStream_t stream) {
    const float2* pos  = (const float2*)d_in[0];   // node_pos [N,2] f32
    const int* batch   = (const int*)d_in[3];      // batch_index [N]
    const int* epi     = (const int*)d_in[4];      // edge_pair_index [2,2,P]
    float* out         = (float*)d_out;            // [128] f32

    int N = in_sizes[0] / 2;
    int P = in_sizes[4] / 4;

    const int nblocks = 2048;
    size_t node4_bytes    = (size_t)N * sizeof(float4);
    size_t partials_bytes = (size_t)NG * nblocks * sizeof(float);

    if (ws_size >= node4_bytes + partials_bytes && (P & 7) == 0) {
        float4* node4   = (float4*)d_ws;
        float* partials = (float*)((char*)d_ws + node4_bytes);
        int nocts = P / 8;
        build_nodes<<<(N + 255) / 256, 256, 0, stream>>>(pos, batch, node4, N);
        xing_partials8<<<nblocks, 256, 0, stream>>>(node4, pos, batch, epi, partials,
                                                    P, nocts, nblocks);
        reduce_partials<<<NG, 256, 0, stream>>>(partials, out, nblocks);
    } else if (ws_size >= partials_bytes) {
        float* partials = (float*)d_ws;
        int nquads = (P & 3) == 0 ? P / 4 : 0;
        xing_partials_basic<<<nblocks, 256, 0, stream>>>(pos, batch, epi, partials,
                                                         P, nquads, nblocks);
        reduce_partials<<<NG, 256, 0, stream>>>(partials, out, nblocks);
    } else {
        zero_out_k<<<1, NG, 0, stream>>>(out);
        int nquads = (P & 3) == 0 ? P / 4 : 0;
        xing_atomic<<<1024, 256, 0, stream>>>(pos, batch, epi, out, P, nquads);
    }
}

// Round 4
// 574.884 us; speedup vs baseline: 1.0558x; 1.0010x over previous
//
#include <hip/hip_runtime.h>

#define NG 128  // NUM_GRAPHS

typedef int v4i __attribute__((ext_vector_type(4)));  // native vector: nontemporal-load OK

__device__ __forceinline__ int seg_cross(float2 p1, float2 p2, float2 p3, float2 p4) {
    const float eps = 1e-5f;
    float ax = p4.x - p3.x, ay = p4.y - p3.y;
    float d1 = ax * (p1.y - p3.y) - ay * (p1.x - p3.x);
    float d2 = ax * (p2.y - p3.y) - ay * (p2.x - p3.x);
    float bx = p2.x - p1.x, by = p2.y - p1.y;
    float d3 = bx * (p3.y - p1.y) - by * (p3.x - p1.x);
    float d4 = bx * (p4.y - p1.y) - by * (p4.x - p1.x);
    return (d1 * d2 < -eps) & (d3 * d4 < -eps);
}

// Stage {pos.x, pos.y, batch} into one 16B record so the s1 gather fetches both.
__global__ __launch_bounds__(256) void build_nodes(
    const float2* __restrict__ pos, const int* __restrict__ batch,
    float4* __restrict__ node4, int N)
{
    int i = blockIdx.x * 256 + threadIdx.x;
    if (i < N) {
        float2 p = pos[i];
        node4[i] = make_float4(p.x, p.y, __int_as_float(batch[i]), 0.0f);
    }
}

// One pipeline group: 4 pairs = 4 idx vectors + 16 gathers.
struct GrpIdx { v4i s1, e1, s2, e2; };
struct GrpRes { float4 n1[4]; float2 q2[4], q3[4], q4[4]; };

__device__ __forceinline__ void load_idx(GrpIdx& g, const v4i* s1p, const v4i* e1p,
                                         const v4i* s2p, const v4i* e2p, int o)
{
    g.s1 = __builtin_nontemporal_load(&s1p[o]);
    g.e1 = __builtin_nontemporal_load(&e1p[o]);
    g.s2 = __builtin_nontemporal_load(&s2p[o]);
    g.e2 = __builtin_nontemporal_load(&e2p[o]);
}

__device__ __forceinline__ void issue_gathers(GrpRes& r, const GrpIdx& g,
                                              const float4* __restrict__ node4,
                                              const float2* __restrict__ pos)
{
    r.n1[0] = node4[g.s1.x]; r.n1[1] = node4[g.s1.y];
    r.n1[2] = node4[g.s1.z]; r.n1[3] = node4[g.s1.w];
    r.q2[0] = pos[g.e1.x]; r.q2[1] = pos[g.e1.y]; r.q2[2] = pos[g.e1.z]; r.q2[3] = pos[g.e1.w];
    r.q3[0] = pos[g.s2.x]; r.q3[1] = pos[g.s2.y]; r.q3[2] = pos[g.s2.z]; r.q3[3] = pos[g.s2.w];
    r.q4[0] = pos[g.e2.x]; r.q4[1] = pos[g.e2.y]; r.q4[2] = pos[g.e2.z]; r.q4[3] = pos[g.e2.w];
}

__device__ __forceinline__ void compute_grp(const GrpRes& r, int* bins)
{
    #pragma unroll
    for (int j = 0; j < 4; j++) {
        if (seg_cross(make_float2(r.n1[j].x, r.n1[j].y), r.q2[j], r.q3[j], r.q4[j]))
            atomicAdd(&bins[__float_as_int(r.n1[j].z)], 1);
    }
}

// 3-stage pipelined gather kernel: idx(k+2) -> gathers(k+1) -> compute(k).
// Issue ORDER matters: idx loads for k+2 go out BEFORE gathers of k+1, so the
// implicit vmcnt wait at compute(k) leaves gathers(k+1)+idx(k+2) in flight.
__global__ __launch_bounds__(256, 3) void xing_pipe(
    const float4* __restrict__ node4, const float2* __restrict__ pos,
    const int* __restrict__ batch,
    const int* __restrict__ epi, float* __restrict__ partials,
    int P, int ngroups, int nblocks)
{
    __shared__ int bins[NG];
    for (int i = threadIdx.x; i < NG; i += 256) bins[i] = 0;
    __syncthreads();

    const v4i* s1p = (const v4i*)(epi);
    const v4i* s2p = (const v4i*)(epi + (size_t)P);
    const v4i* e1p = (const v4i*)(epi + 2 * (size_t)P);
    const v4i* e2p = (const v4i*)(epi + 3 * (size_t)P);

    int tid = blockIdx.x * 256 + threadIdx.x;
    int stride = gridDim.x * 256;

    if (tid < ngroups) {
        GrpIdx idxA, idxB;
        GrpRes resA, resB;
        // prologue: idx(k), idx(k+1), gathers(k)
        int last = ngroups - 1;
        int o1 = tid + stride;       if (o1 > last) o1 = last;
        load_idx(idxA, s1p, e1p, s2p, e2p, tid);
        load_idx(idxB, s1p, e1p, s2p, e2p, o1);
        issue_gathers(resA, idxA, node4, pos);

        for (int o = tid; o < ngroups; ) {
            // half 1: compute A, gathers B, prefetch idx into A's slot
            int op = o + 2 * stride; if (op > last) op = last;
            load_idx(idxA, s1p, e1p, s2p, e2p, op);
            issue_gathers(resB, idxB, node4, pos);
            compute_grp(resA, bins);
            o += stride;
            if (o >= ngroups) break;
            // half 2: compute B, gathers A, prefetch idx into B's slot
            op = o + 2 * stride; if (op > last) op = last;
            load_idx(idxB, s1p, e1p, s2p, e2p, op);
            issue_gathers(resA, idxA, node4, pos);
            compute_grp(resB, bins);
            o += stride;
        }
    }

    // tail (P not multiple of 4)
    for (int i = ngroups * 4 + tid; i < P; i += stride) {
        int s1 = epi[i];
        int s2 = epi[(size_t)P + i];
        int e1 = epi[2 * (size_t)P + i];
        int e2 = epi[3 * (size_t)P + i];
        if (seg_cross(pos[s1], pos[e1], pos[s2], pos[e2]))
            atomicAdd(&bins[batch[s1]], 1);
    }

    __syncthreads();
    for (int i = threadIdx.x; i < NG; i += 256)
        partials[(size_t)i * nblocks + blockIdx.x] = (float)bins[i];
}

// Fallback when ws can't hold the node4 table.
__global__ __launch_bounds__(256) void xing_partials_basic(
    const float2* __restrict__ pos, const int* __restrict__ batch,
    const int* __restrict__ epi, float* __restrict__ partials,
    int P, int nquads, int nblocks)
{
    __shared__ int bins[NG];
    for (int i = threadIdx.x; i < NG; i += 256) bins[i] = 0;
    __syncthreads();
    const int4* s1p = (const int4*)(epi);
    const int4* s2p = (const int4*)(epi + (size_t)P);
    const int4* e1p = (const int4*)(epi + 2 * (size_t)P);
    const int4* e2p = (const int4*)(epi + 3 * (size_t)P);
    int tid = blockIdx.x * 256 + threadIdx.x;
    int stride = gridDim.x * 256;
    for (int q = tid; q < nquads; q += stride) {
        int4 s1 = s1p[q], e1 = e1p[q], s2 = s2p[q], e2 = e2p[q];
        float2 a1 = pos[s1.x], a2 = pos[e1.x], a3 = pos[s2.x], a4 = pos[e2.x];
        float2 b1 = pos[s1.y], b2 = pos[e1.y], b3 = pos[s2.y], b4 = pos[e2.y];
        float2 c1 = pos[s1.z], c2 = pos[e1.z], c3 = pos[s2.z], c4 = pos[e2.z];
        float2 d1 = pos[s1.w], d2 = pos[e1.w], d3 = pos[s2.w], d4 = pos[e2.w];
        int ba = batch[s1.x], bb = batch[s1.y], bc = batch[s1.z], bd = batch[s1.w];
        if (seg_cross(a1, a2, a3, a4)) atomicAdd(&bins[ba], 1);
        if (seg_cross(b1, b2, b3, b4)) atomicAdd(&bins[bb], 1);
        if (seg_cross(c1, c2, c3, c4)) atomicAdd(&bins[bc], 1);
        if (seg_cross(d1, d2, d3, d4)) atomicAdd(&bins[bd], 1);
    }
    for (int i = nquads * 4 + tid; i < P; i += stride) {
        int s1 = epi[i], s2 = epi[(size_t)P + i], e1 = epi[2 * (size_t)P + i], e2 = epi[3 * (size_t)P + i];
        if (seg_cross(pos[s1], pos[e1], pos[s2], pos[e2])) atomicAdd(&bins[batch[s1]], 1);
    }
    __syncthreads();
    for (int i = threadIdx.x; i < NG; i += 256)
        partials[(size_t)i * nblocks + blockIdx.x] = (float)bins[i];
}

__global__ __launch_bounds__(256) void reduce_partials(
    const float* __restrict__ partials, float* __restrict__ out, int nblocks)
{
    int bin = blockIdx.x;
    const float* row = partials + (size_t)bin * nblocks;
    float sum = 0.0f;
    for (int i = threadIdx.x; i < nblocks; i += 256) sum += row[i];
    #pragma unroll
    for (int off = 32; off > 0; off >>= 1) sum += __shfl_down(sum, off, 64);
    __shared__ float ws[4];
    int lane = threadIdx.x & 63, wid = threadIdx.x >> 6;
    if (lane == 0) ws[wid] = sum;
    __syncthreads();
    if (threadIdx.x == 0) out[bin] = ws[0] + ws[1] + ws[2] + ws[3];
}

__global__ void zero_out_k(float* out) { out[threadIdx.x] = 0.0f; }

__global__ __launch_bounds__(256) void xing_atomic(
    const float2* __restrict__ pos, const int* __restrict__ batch,
    const int* __restrict__ epi, float* __restrict__ out, int P, int nquads)
{
    __shared__ int bins[NG];
    for (int i = threadIdx.x; i < NG; i += 256) bins[i] = 0;
    __syncthreads();
    const int4* s1p = (const int4*)(epi);
    const int4* s2p = (const int4*)(epi + (size_t)P);
    const int4* e1p = (const int4*)(epi + 2 * (size_t)P);
    const int4* e2p = (const int4*)(epi + 3 * (size_t)P);
    int tid = blockIdx.x * 256 + threadIdx.x;
    int stride = gridDim.x * 256;
    for (int q = tid; q < nquads; q += stride) {
        int4 s1 = s1p[q], e1 = e1p[q], s2 = s2p[q], e2 = e2p[q];
        if (seg_cross(pos[s1.x], pos[e1.x], pos[s2.x], pos[e2.x])) atomicAdd(&bins[batch[s1.x]], 1);
        if (seg_cross(pos[s1.y], pos[e1.y], pos[s2.y], pos[e2.y])) atomicAdd(&bins[batch[s1.y]], 1);
        if (seg_cross(pos[s1.z], pos[e1.z], pos[s2.z], pos[e2.z])) atomicAdd(&bins[batch[s1.z]], 1);
        if (seg_cross(pos[s1.w], pos[e1.w], pos[s2.w], pos[e2.w])) atomicAdd(&bins[batch[s1.w]], 1);
    }
    for (int i = nquads * 4 + tid; i < P; i += stride) {
        int s1 = epi[i], s2 = epi[(size_t)P + i], e1 = epi[2 * (size_t)P + i], e2 = epi[3 * (size_t)P + i];
        if (seg_cross(pos[s1], pos[e1], pos[s2], pos[e2])) atomicAdd(&bins[batch[s1]], 1);
    }
    __syncthreads();
    for (int i = threadIdx.x; i < NG; i += 256) {
        int v = bins[i];
        if (v) atomicAdd(&out[i], (float)v);
    }
}

extern "C" void kernel_launch(void* const* d_in, const int* in_sizes, int n_in,
                              void* d_out, int out_size, void* d_ws, size_t ws_size,
                              hipStream_t stream) {
    const float2* pos  = (const float2*)d_in[0];   // node_pos [N,2] f32
    const int* batch   = (const int*)d_in[3];      // batch_index [N]
    const int* epi     = (const int*)d_in[4];      // edge_pair_index [2,2,P]
    float* out         = (float*)d_out;            // [128] f32

    int N = in_sizes[0] / 2;
    int P = in_sizes[4] / 4;

    const int nblocks = 2048;
    size_t node4_bytes    = (size_t)N * sizeof(float4);
    size_t partials_bytes = (size_t)NG * nblocks * sizeof(float);

    if (ws_size >= node4_bytes + partials_bytes) {
        float4* node4   = (float4*)d_ws;
        float* partials = (float*)((char*)d_ws + node4_bytes);
        int ngroups = P / 4;  // groups of 4 pairs; remainder via tail loop
        build_nodes<<<(N + 255) / 256, 256, 0, stream>>>(pos, batch, node4, N);
        xing_pipe<<<nblocks, 256, 0, stream>>>(node4, pos, batch, epi, partials,
                                               P, ngroups, nblocks);
        reduce_partials<<<NG, 256, 0, stream>>>(partials, out, nblocks);
    } else if (ws_size >= partials_bytes) {
        float* partials = (float*)d_ws;
        int nquads = P / 4;
        xing_partials_basic<<<nblocks, 256, 0, stream>>>(pos, batch, epi, partials,
                                                         P, nquads, nblocks);
        reduce_partials<<<NG, 256, 0, stream>>>(partials, out, nblocks);
    } else {
        zero_out_k<<<1, NG, 0, stream>>>(out);
        int nquads = P / 4;
        xing_atomic<<<1024, 256, 0, stream>>>(pos, batch, epi, out, P, nquads);
    }
}